// Round 12
// baseline (214.272 us; speedup 1.0000x reference)
//
#include <hip/hip_runtime.h>
#include <math.h>

#define B_    8
#define N_    1024
#define FIN   512
#define FOUT  256
#define H_    8
#define ALPHA 0.2f

#define XT (B_ * N_ * FIN)     // 4194304 x elements
#define WT (H_ * FOUT * FIN)   // 1048576 W elements

typedef short s16x8 __attribute__((ext_vector_type(8)));
typedef float f32x4 __attribute__((ext_vector_type(4)));

__device__ __forceinline__ unsigned short f2bf(float f) {
  unsigned int u = __float_as_uint(f);
  u = (u + 0x7FFFu + ((u >> 16) & 1u)) >> 16;   // round-to-nearest-even
  return (unsigned short)u;
}

// pack 4 fp32 -> 4 OCP e4m3 bytes (v_cvt_pk_fp8_f32; OCP format on gfx950)
__device__ __forceinline__ unsigned int pk4_fp8(float a, float b, float c,
                                                float d) {
  int u = __builtin_amdgcn_cvt_pk_fp8_f32(a, b, 0, false);   // bytes 0,1
  u = __builtin_amdgcn_cvt_pk_fp8_f32(c, d, u, true);        // bytes 2,3
  return (unsigned int)u;
}

// ---------------------------------------------------------------------------
// Fragment layouts (lane-linear):
//  bf16 frags are 16 B/lane -> 1024 B per block; fp8 frags 8 B/lane -> 512 B.
//  xq (proj A): block ((b*64+mb)*16 + fb), lane byte l*16, holds
//      x[b][n=mb*16+col][f=fb*32+quad*8+j] (bf16)
//  Wq (proj B): block ((h*16+otg)*16 + fb), holds W[h][o=otg*16+col][f=...]
//  htq (pv B):  block ((hb*16+otg)*32 + kk), byte quad*128+col*8+j =
//      h[hb][k=kk*32+quad*8+j][o=otg*16+col] (fp8)
//  wq  (pv A):  block ((hb*64+rb)*32 + kk) = softmax weights (fp8)
// A wave's access is base + lane*(8|16): one coalesced 512/1024 B op.
// ---------------------------------------------------------------------------

// ---------------------------------------------------------------------------
// Kernel 0: prep — x,W -> bf16 FRAGMENT layouts + zero f1/f2 + adj bit-pack.
// ---------------------------------------------------------------------------
#define XQB  2048    // xq frag blocks (8192 waves)
#define WQB  512     // Wq frag blocks (2048 waves)
#define ZRB  128     // zero blocks
#define PKB  ((B_ * N_ * 32) / 256)      // 1024 adj-pack blocks

__global__ __launch_bounds__(256) void prep(
    const float* __restrict__ x, const float* __restrict__ W,
    const int* __restrict__ adj, unsigned short* __restrict__ xq,
    unsigned short* __restrict__ Wq, float* __restrict__ f12,
    unsigned int* __restrict__ adjP) {
  const int blk = blockIdx.x;
  const int w = threadIdx.x >> 6, l = threadIdx.x & 63;
  const int col = l & 15, qd = l >> 4;

  if (blk < XQB) {           // ---- xq: x -> A-fragment bf16 ----
    const int wv = blk * 4 + w;
    const int b = wv >> 10, rest = wv & 1023;
    const int mb = rest >> 4, fb = rest & 15;
    const float* src = x + ((size_t)(b * N_ + mb * 16 + col)) * FIN +
                       fb * 32 + qd * 8;
    float4 v0 = *(const float4*)src;
    float4 v1 = *(const float4*)(src + 4);
    s16x8 sv;
    sv[0] = (short)f2bf(v0.x); sv[1] = (short)f2bf(v0.y);
    sv[2] = (short)f2bf(v0.z); sv[3] = (short)f2bf(v0.w);
    sv[4] = (short)f2bf(v1.x); sv[5] = (short)f2bf(v1.y);
    sv[6] = (short)f2bf(v1.z); sv[7] = (short)f2bf(v1.w);
    *(s16x8*)((unsigned char*)xq +
              (((size_t)(b * 64 + mb) * 16 + fb) << 10) + l * 16) = sv;
    return;
  }
  if (blk < XQB + WQB) {     // ---- Wq: W -> B-fragment bf16 ----
    const int wv = (blk - XQB) * 4 + w;
    const int h = wv >> 8, rest = wv & 255;
    const int otg = rest >> 4, fb = rest & 15;
    const float* src = W + ((size_t)(h * FOUT + otg * 16 + col)) * FIN +
                       fb * 32 + qd * 8;
    float4 v0 = *(const float4*)src;
    float4 v1 = *(const float4*)(src + 4);
    s16x8 sv;
    sv[0] = (short)f2bf(v0.x); sv[1] = (short)f2bf(v0.y);
    sv[2] = (short)f2bf(v0.z); sv[3] = (short)f2bf(v0.w);
    sv[4] = (short)f2bf(v1.x); sv[5] = (short)f2bf(v1.y);
    sv[6] = (short)f2bf(v1.z); sv[7] = (short)f2bf(v1.w);
    *(s16x8*)((unsigned char*)Wq +
              (((size_t)(h * 16 + otg) * 16 + fb) << 10) + l * 16) = sv;
    return;
  }
  if (blk < XQB + WQB + ZRB) {   // ---- zero f1/f2 ----
    const int i = (blk - XQB - WQB) * 256 + threadIdx.x;
    ((float4*)f12)[i] = make_float4(0.f, 0.f, 0.f, 0.f);
    return;
  }
  // ---- pack adj (byte-transposed) ----
  const int dw = (blk - XQB - WQB - ZRB) * 256 + threadIdx.x;
  const int r = dw >> 5, pd = dw & 31;
  const int q = pd >> 3, c8 = pd & 7;                    // c8 = kk>>2
  const int* ap = adj + (size_t)r * N_;
  unsigned int out = 0;
#pragma unroll
  for (int i = 0; i < 4; ++i) {        // byte i: kk = c8*4+i
    const int jb = (c8 * 4 + i) * 32 + q * 8;
    int4 v0 = *(const int4*)(ap + jb);
    int4 v1 = *(const int4*)(ap + jb + 4);
    unsigned int byte = 0;
    byte |= (v0.x ? 1u : 0u) << 0; byte |= (v0.y ? 1u : 0u) << 1;
    byte |= (v0.z ? 1u : 0u) << 2; byte |= (v0.w ? 1u : 0u) << 3;
    byte |= (v1.x ? 1u : 0u) << 4; byte |= (v1.y ? 1u : 0u) << 5;
    byte |= (v1.z ? 1u : 0u) << 6; byte |= (v1.w ? 1u : 0u) << 7;
    out |= byte << (i * 8);
  }
  adjP[dw] = out;
}

// ---------------------------------------------------------------------------
// Kernel 1: proj — BARRIER-FREE streaming bf16 MFMA GEMM (pv pattern).
// No LDS. Wave = 32 m-rows x 64 o-cols; per fb: 6 coalesced 1KB loads
// (2 A + 4 B) -> 8 MFMAs. Grid 2048 (b low bits: xq[b] 1MB + Wq 2MB live in
// one XCD L2). Epilogue: fp8 frag htq store + fused f1/f2 (atomicAdd).
// ---------------------------------------------------------------------------
__global__ __launch_bounds__(256) void proj_mfma(
    const unsigned short* __restrict__ xq, const unsigned short* __restrict__ Wq,
    const float* __restrict__ a1, const float* __restrict__ a2,
    unsigned char* __restrict__ htq, float* __restrict__ f1,
    float* __restrict__ f2) {
  const int blk = blockIdx.x;
  const int b = blk & 7;
  const int h = (blk >> 3) & 7;
  const int oq = (blk >> 6) & 3;
  const int mgg = blk >> 8;            // 0..7
  const int w = threadIdx.x >> 6, l = threadIdx.x & 63;
  const int col = l & 15, quad = l >> 4;
  const int mg = mgg * 4 + w;          // 0..31: m rows [mg*32, +32)
  const int hb = h * B_ + b;

  const unsigned char* ap = (const unsigned char*)xq +
      (((size_t)(b * 64 + mg * 2) * 16) << 10) + l * 16;
  const unsigned char* bp = (const unsigned char*)Wq +
      (((size_t)(h * 16 + oq * 4) * 16) << 10) + l * 16;

  f32x4 acc[2][4];
  const f32x4 z4 = {0.f, 0.f, 0.f, 0.f};
#pragma unroll
  for (int g = 0; g < 2; ++g)
#pragma unroll
    for (int t = 0; t < 4; ++t) acc[g][t] = z4;

#pragma unroll 4
  for (int fb = 0; fb < 16; ++fb) {
    const s16x8 af0 = *(const s16x8*)(ap + (fb << 10));
    const s16x8 af1 = *(const s16x8*)(ap + 16384 + (fb << 10));
#pragma unroll
    for (int t = 0; t < 4; ++t) {
      const s16x8 bf = *(const s16x8*)(bp + (((t * 16) + fb) << 10));
      acc[0][t] = __builtin_amdgcn_mfma_f32_16x16x32_bf16(af0, bf, acc[0][t],
                                                          0, 0, 0);
      acc[1][t] = __builtin_amdgcn_mfma_f32_16x16x32_bf16(af1, bf, acc[1][t],
                                                          0, 0, 0);
    }
  }

  // epilogue: fp8 frag htq store (kk = mg) + fused f1/f2 partials
  float pf1[2][4] = {{0.f}}, pf2[2][4] = {{0.f}};
#pragma unroll
  for (int g = 0; g < 2; ++g) {
#pragma unroll
    for (int t = 0; t < 4; ++t) {
      const int o = (oq * 4 + t) * 16 + col;
      const float va1 = a1[h * FOUT + o], va2 = a2[h * FOUT + o];
      const int otg = oq * 4 + t;
      unsigned char* fb_out =
          htq + (((size_t)(hb * 16 + otg) * 32 + mg) << 9);
      const unsigned int qv =
          pk4_fp8(acc[g][t][0], acc[g][t][1], acc[g][t][2], acc[g][t][3]);
      *(unsigned int*)(fb_out + (g * 2 + (quad >> 1)) * 128 + col * 8 +
                       (quad & 1) * 4) = qv;
#pragma unroll
      for (int r = 0; r < 4; ++r) {
        pf1[g][r] += acc[g][t][r] * va1;
        pf2[g][r] += acc[g][t][r] * va2;
      }
    }
  }
#pragma unroll
  for (int off = 1; off <= 8; off <<= 1)
#pragma unroll
    for (int g = 0; g < 2; ++g)
#pragma unroll
      for (int r = 0; r < 4; ++r) {
        pf1[g][r] += __shfl_xor(pf1[g][r], off);
        pf2[g][r] += __shfl_xor(pf2[g][r], off);
      }
  if (col == 0) {
#pragma unroll
    for (int g = 0; g < 2; ++g)
#pragma unroll
      for (int r = 0; r < 4; ++r) {
        const int n = mg * 32 + g * 16 + quad * 4 + r;
        atomicAdd(&f1[hb * N_ + n], pf1[g][r]);
        atomicAdd(&f2[hb * N_ + n], pf2[g][r]);
      }
  }
}

// ---------------------------------------------------------------------------
// Kernel 2: wgen — softmax weights -> fp8, written in A-fragment layout.
// (unchanged from R10/R11)
// ---------------------------------------------------------------------------
__global__ __launch_bounds__(256) void wgen(
    const float* __restrict__ f1, const float* __restrict__ f2,
    const unsigned int* __restrict__ adjP, unsigned char* __restrict__ wq) {
  const int id = blockIdx.x;
  const int b = id & 7, h = (id >> 3) & 7;
  const int rbg = (id >> 6) & 15;
  const int kkh = id >> 10;            // kk half: [kkh*16, +16)
  const int w = threadIdx.x >> 6, lane = threadIdx.x & 63;
  const int col = lane & 15, quad = lane >> 4;
  const int hb = h * B_ + b;
  const int rb = rbg * 4 + w;
  const int row = rb * 16 + col;

  // per-wave M2 = max_j f2[hb][j]
  const float* f2r = f2 + (size_t)hb * N_;
  float m2 = -3.0e38f;
#pragma unroll
  for (int c = 0; c < 16; ++c) m2 = fmaxf(m2, f2r[lane + c * 64]);
#pragma unroll
  for (int off = 32; off; off >>= 1) m2 = fmaxf(m2, __shfl_xor(m2, off));

  const float f1i = f1[(size_t)hb * N_ + row];
  const float tb = f1i + m2;
  const float mhat = fmaxf(tb, ALPHA * tb);   // >= leaky(f1i+f2j) for all j

  const unsigned int* adp = adjP + ((size_t)(b * N_ + row) << 5) + quad * 8;
  const float* f2p = f2r + quad * 8;
  unsigned char* wp = wq + (((size_t)(hb * 64 + rb) * 32) << 9) + lane * 8;

#pragma unroll
  for (int k4i = 0; k4i < 4; ++k4i) {
    const int k4 = kkh * 4 + k4i;
    const unsigned int ad = adp[k4];
#pragma unroll
    for (int k2 = 0; k2 < 4; ++k2) {
      const int kk = k4 * 4 + k2;
      const unsigned int ab = (ad >> (k2 * 8)) & 0xFFu;
      const float4 fA = *(const float4*)(f2p + kk * 32);
      const float4 fB = *(const float4*)(f2p + kk * 32 + 4);
      float ex[8];
#pragma unroll
      for (int j = 0; j < 8; ++j) {
        const float fv = j < 4 ? ((const float*)&fA)[j]
                               : ((const float*)&fB)[j - 4];
        const float tt = f1i + fv;
        const float l = fmaxf(tt, ALPHA * tt);
        const float p = __expf(l - mhat);
        ex[j] = ((ab >> j) & 1u) ? p : 0.f;
      }
      const unsigned int lo = pk4_fp8(ex[0], ex[1], ex[2], ex[3]);
      const unsigned int hi = pk4_fp8(ex[4], ex[5], ex[6], ex[7]);
      *(uint2*)(wp + kk * 512) = make_uint2(lo, hi);
    }
  }
}

// ---------------------------------------------------------------------------
// Kernel 3: pv — pure fp8 MFMA GEMM, fat tile 32 rows x 64 cols x 2 heads.
// (unchanged from R11)
// ---------------------------------------------------------------------------
__global__ __launch_bounds__(256, 4) void pv(
    const unsigned char* __restrict__ htq, const unsigned char* __restrict__ wq,
    float* __restrict__ p0, float* __restrict__ p1, float* __restrict__ p2,
    float* __restrict__ p3) {
  const int id = blockIdx.x;
  const int b = id & 7;                // XCD-keyed
  const int g0 = (id >> 3) & 3;        // heads {2g0, 2g0+1}
  const int oq = (id >> 5) & 3;        // o-quarter: otg in [oq*4, +4)
  const int it = id >> 7;              // 0..7 (128-row groups)
  const int w = threadIdx.x >> 6, lane = threadIdx.x & 63;
  const int col = lane & 15, quad = lane >> 4;
  const int rb = it * 8 + w * 2;       // this wave's rows [rb*16, rb*16+32)

  float hsum[2][4][4];
#pragma unroll
  for (int g = 0; g < 2; ++g)
#pragma unroll
    for (int t = 0; t < 4; ++t)
#pragma unroll
      for (int r = 0; r < 4; ++r) hsum[g][t][r] = 0.f;

  const long ones = 0x3838383838383838L;   // 8x fp8 e4m3 1.0

  for (int hh = 0; hh < 2; ++hh) {
    const int hb = (g0 * 2 + hh) * B_ + b;
    const unsigned char* ap =
        wq + (((size_t)(hb * 64 + rb) * 32) << 9) + lane * 8;
    const unsigned char* bp =
        htq + (((size_t)(hb * 16 + oq * 4) * 32) << 9) + lane * 8;

    f32x4 acc[2][4], accs[2];
    const f32x4 z4 = {0.f, 0.f, 0.f, 0.f};
#pragma unroll
    for (int g = 0; g < 2; ++g) {
      accs[g] = z4;
#pragma unroll
      for (int t = 0; t < 4; ++t) acc[g][t] = z4;
    }

#pragma unroll 2
    for (int kk = 0; kk < 32; ++kk) {
      const long af0 = *(const long*)(ap + kk * 512);
      const long af1 = *(const long*)(ap + 16384 + kk * 512);  // block rb+1
      accs[0] = __builtin_amdgcn_mfma_f32_16x16x32_fp8_fp8(af0, ones, accs[0], 0, 0, 0);
      accs[1] = __builtin_amdgcn_mfma_f32_16x16x32_fp8_fp8(af1, ones, accs[1], 0, 0, 0);
#pragma unroll
      for (int t = 0; t < 4; ++t) {
        const long bf = *(const long*)(bp + ((t * 32 + kk) << 9));
        acc[0][t] = __builtin_amdgcn_mfma_f32_16x16x32_fp8_fp8(af0, bf,
                                                               acc[0][t], 0, 0, 0);
        acc[1][t] = __builtin_amdgcn_mfma_f32_16x16x32_fp8_fp8(af1, bf,
                                                               acc[1][t], 0, 0, 0);
      }
    }

    // normalize (denom = ones-column, same quantized weights), ELU, head-sum
#pragma unroll
    for (int g = 0; g < 2; ++g)
#pragma unroll
      for (int r = 0; r < 4; ++r) {
        const float inv = 1.0f / accs[g][r];
#pragma unroll
        for (int t = 0; t < 4; ++t) {
          const float oh = acc[g][t][r] * inv;
          hsum[g][t][r] += oh > 0.f ? oh : __expf(oh) - 1.f;
        }
      }
  }

  // ---- write head-pair partial: row (rb+g)*16+quad*4+r, col oq*64+t*16+col
  float* pdst = (g0 == 0) ? p0 : (g0 == 1) ? p1 : (g0 == 2) ? p2 : p3;
#pragma unroll
  for (int g = 0; g < 2; ++g)
#pragma unroll
    for (int t = 0; t < 4; ++t)
#pragma unroll
      for (int r = 0; r < 4; ++r) {
        const int orow = (rb + g) * 16 + quad * 4 + r;
        pdst[(size_t)(b * N_ + orow) * FOUT + oq * 64 + t * 16 + col] =
            hsum[g][t][r];
      }
}

// ---------------------------------------------------------------------------
// Kernel 4: sum 4 head-pair partials + log_softmax over o. Wave per row.
// ---------------------------------------------------------------------------
__global__ __launch_bounds__(256) void logsm(
    const float* __restrict__ p0, const float* __restrict__ p1,
    const float* __restrict__ p2, const float* __restrict__ p3,
    float* __restrict__ out) {
  const int row = blockIdx.x * 4 + (threadIdx.x >> 6);
  const int lane = threadIdx.x & 63;
  const size_t base = (size_t)row * FOUT;
  float v[4];
  float m = -3.0e38f;
#pragma unroll
  for (int c = 0; c < 4; ++c) {
    const size_t idx = base + c * 64 + lane;
    v[c] = p0[idx] + p1[idx] + p2[idx] + p3[idx];
    m = fmaxf(m, v[c]);
  }
#pragma unroll
  for (int off = 32; off; off >>= 1) m = fmaxf(m, __shfl_xor(m, off));
  float s = 0.f;
#pragma unroll
  for (int c = 0; c < 4; ++c) s += __expf(v[c] - m);
#pragma unroll
  for (int off = 32; off; off >>= 1) s += __shfl_xor(s, off);
  const float lg = m + logf(s);
#pragma unroll
  for (int c = 0; c < 4; ++c)
    out[base + c * 64 + lane] = v[c] - lg;
}

// ---------------------------------------------------------------------------
extern "C" void kernel_launch(void* const* d_in, const int* in_sizes, int n_in,
                              void* d_out, int out_size, void* d_ws,
                              size_t ws_size, hipStream_t stream) {
  const float* x   = (const float*)d_in[0];
  const int*   adj = (const int*)d_in[1];
  const float* W   = (const float*)d_in[2];
  const float* a1  = (const float*)d_in[3];
  const float* a2  = (const float*)d_in[4];
  float* out = (float*)d_out;

  unsigned char* htq = (unsigned char*)d_ws;                          // 16 MB fp8 h (frag)
  unsigned short* xq = (unsigned short*)(htq + (size_t)H_ * B_ * FOUT * N_); // 8 MB bf16 A-frag
  unsigned short* Wq = xq + (size_t)XT;                               // 2 MB bf16 B-frag
  float* f1 = (float*)(Wq + (size_t)WT);                              // 256 KB
  float* f2 = f1 + (size_t)H_ * B_ * N_;                              // 256 KB
  float* part2 = f2 + (size_t)H_ * B_ * N_;                           // 8 MB
  float* part3 = part2 + (size_t)B_ * N_ * FOUT;                      // 8 MB
  unsigned int* adjP = (unsigned int*)(part3 + (size_t)B_ * N_ * FOUT); // 1 MB
  unsigned char* wq = (unsigned char*)(adjP + (size_t)B_ * N_ * 32);  // 64 MB fp8 weights
  float* part1 = (float*)xq;   // xq dead after proj_mfma (8 MB reuse)

  prep<<<XQB + WQB + ZRB + PKB, 256, 0, stream>>>(x, W, adj, xq, Wq, f1, adjP);

  proj_mfma<<<2048, 256, 0, stream>>>(xq, Wq, a1, a2, htq, f1, f2);

  wgen<<<2048, 256, 0, stream>>>(f1, f2, adjP, wq);

  pv<<<1024, 256, 0, stream>>>(htq, wq, out, part1, part2, part3);

  logsm<<<(B_ * N_) / 4, 256, 0, stream>>>(out, part1, part2, part3, out);
}